// Round 11
// baseline (382.787 us; speedup 1.0000x reference)
//
#include <hip/hip_runtime.h>
#include <hip/hip_bf16.h>

// TensorTrainLMN: out[b, a*128+h] = X[b,:] @ W[:, a*128+h] + bias
//   X[b] = [nh[b,0,:128], ..., nh[b,15,:128], te[b,:128]]   (K = 2176)
// tt_fold: folds A@B^(15-c)@U_out (exact f32) into W bf16, PRE-PACKED in MFMA
//   B-fragment order: Wp[kt][slot=k8][n 0..511][8 bf16]. (verified r5-r10)
// tt_gemm (NEW): barrier-free, LDS-free. 512-thr blocks = 8 INDEPENDENT waves
//   (2M x 4N of 64x64 wave tiles) co-located for L1 reuse (n-waves share A
//   addresses, m-pairs share B frags). A loaded straight into MFMA fragment
//   layout from global (lane: row fm*16+lx, k lg*8+j -> 2x float4, 16x128B
//   coalesced segments), cvt_pk to bf16 in regs. B: verified reg double-buffer
//   from L2-resident Wp, distance-1. Ordering = compiler counted waits only.

typedef short bf16x8 __attribute__((ext_vector_type(8)));
typedef float f32x4  __attribute__((ext_vector_type(4)));

__device__ __forceinline__ unsigned f2bfbits(float f) {
    unsigned u = __builtin_bit_cast(unsigned, f);
    return (u + 0x7FFFu + ((u >> 16) & 1u)) >> 16;   // round-to-nearest-even
}
// compiler fuses pairs into v_cvt_pk_bf16_f32 (m240)
__device__ __forceinline__ unsigned pack2(float a, float b) {
    unsigned lo = (unsigned)__builtin_bit_cast(unsigned short, __float2bfloat16(a));
    unsigned hi = (unsigned)__builtin_bit_cast(unsigned short, __float2bfloat16(b));
    return lo | (hi << 16);
}

// ---------------------------------------------------------------------------
// Fold kernel: 72 blocks x 512 threads (verified r7-r10).
// ---------------------------------------------------------------------------
#define FS 68   // fold matmul LDS row stride (floats); 16B-aligned, 2-way banks

__global__ __launch_bounds__(512) void tt_fold(
    const float* __restrict__ Ag,    // (4,128,64)
    const float* __restrict__ Bg,    // (4,64,64)
    const float* __restrict__ Abg,   // (4,1,64)
    const float* __restrict__ Utg,   // (4,128,64)
    const float* __restrict__ btg,   // (4,1,64)
    const float* __restrict__ Uog,   // (4,64,128)
    const float* __restrict__ bog,   // (4,1,128)
    unsigned short* __restrict__ Wp, // [34][8][512][8] bf16
    float* __restrict__ biasOut)     // [512]
{
    __shared__ __align__(16) float L[23552];   // 92 KB
    const int t = threadIdx.x;
    const int bid = blockIdx.x;

    auto mm = [&](float* d, const float* x, const float* y, const float* add) {
        const int r = t >> 3, c0 = (t & 7) << 3;
        float acc[8];
#pragma unroll
        for (int j = 0; j < 8; ++j) acc[j] = 0.f;
        for (int k = 0; k < 64; ++k) {
            const float a = x[r * FS + k];
            const float4 y0 = *(const float4*)(y + k * FS + c0);
            const float4 y1 = *(const float4*)(y + k * FS + c0 + 4);
            acc[0] += a * y0.x; acc[1] += a * y0.y;
            acc[2] += a * y0.z; acc[3] += a * y0.w;
            acc[4] += a * y1.x; acc[5] += a * y1.y;
            acc[6] += a * y1.z; acc[7] += a * y1.w;
        }
        if (add) {
#pragma unroll
            for (int j = 0; j < 8; ++j) acc[j] += add[r * FS + c0 + j];
        }
#pragma unroll
        for (int j = 0; j < 8; ++j) d[r * FS + c0 + j] = acc[j];
    };

    float* buf[4];
    buf[0] = L;
    buf[1] = L + 4352;
    buf[2] = L + 8704;
    buf[3] = L + 13056;
    float* const Pbuf = L + 17408;   // 64x64 dense (stride 64)
    float* const UC   = L + 21504;   // 16x128 staging

    if (bid < 68) {
        int a, p, kbase;
        const float* src;
        if (bid < 64) { a = bid >> 4; const int c = bid & 15; p = 15 - c; kbase = c * 128; src = Ag  + a * 8192; }
        else          { a = bid - 64; p = 16; kbase = 2048;               src = Utg + a * 8192; }
        const float* Bmat = Bg + a * 4096;

        for (int i = t; i < 4096; i += 512) {
            const int row = i >> 6, col = i & 63;
            buf[0][row * FS + col] = Bmat[i];
            buf[2][row * FS + col] = (row == col) ? 1.f : 0.f;
        }
        __syncthreads();
        int bcur = 0, rcur = 2;
        int e = p;
        while (e) {
            if (e & 1) { mm(buf[rcur ^ 1], buf[rcur], buf[bcur], nullptr); rcur ^= 1; __syncthreads(); }
            e >>= 1;
            if (e)     { mm(buf[bcur ^ 1], buf[bcur], buf[bcur], nullptr); bcur ^= 1; __syncthreads(); }
        }

        {
            const int prow = t >> 3, pc0 = (t & 7) << 3;
#pragma unroll
            for (int j = 0; j < 8; ++j)
                Pbuf[prow * 64 + pc0 + j] = buf[rcur][prow * FS + pc0 + j];
        }
        __syncthreads();

        // M1 = src(128x64) @ P, stored stride-65 at L (bufs dead now)
        float* M1 = L;
        {
            const int i = t >> 2, r0 = (t & 3) << 4;
            float acc[16];
#pragma unroll
            for (int j = 0; j < 16; ++j) acc[j] = 0.f;
            for (int q = 0; q < 64; ++q) {
                const float av = src[i * 64 + q];
                const float4* pr = (const float4*)(Pbuf + q * 64 + r0);
#pragma unroll
                for (int jj = 0; jj < 4; ++jj) {
                    float4 v = pr[jj];
                    acc[4 * jj + 0] += av * v.x;
                    acc[4 * jj + 1] += av * v.y;
                    acc[4 * jj + 2] += av * v.z;
                    acc[4 * jj + 3] += av * v.w;
                }
            }
#pragma unroll
            for (int j = 0; j < 16; ++j) M1[i * 65 + r0 + j] = acc[j];
        }
        __syncthreads();

        // W2 = M1(128x64) @ Uo(64x128); Uo staged 16 rows/chunk
        const float* UoA = Uog + a * 8192;
        const int i = t >> 2, h0 = (t & 3) << 5;
        float acc2[32];
#pragma unroll
        for (int j = 0; j < 32; ++j) acc2[j] = 0.f;
        for (int ch = 0; ch < 4; ++ch) {
            __syncthreads();
            for (int idx = t; idx < 2048; idx += 512) UC[idx] = UoA[ch * 2048 + idx];
            __syncthreads();
            for (int rr = 0; rr < 16; ++rr) {
                const float m = M1[i * 65 + ch * 16 + rr];
                const float4* ur = (const float4*)(UC + rr * 128 + h0);
#pragma unroll
                for (int jj = 0; jj < 8; ++jj) {
                    float4 v = ur[jj];
                    acc2[4 * jj + 0] += m * v.x;
                    acc2[4 * jj + 1] += m * v.y;
                    acc2[4 * jj + 2] += m * v.z;
                    acc2[4 * jj + 3] += m * v.w;
                }
            }
        }
        {
            const int k = kbase + i;
            const int kt = k >> 6, slot = (k >> 3) & 7, widx = k & 7;
#pragma unroll
            for (int j = 0; j < 32; ++j) {
                const int n = a * 128 + h0 + j;
                Wp[((size_t)(kt * 8 + slot) * 512 + n) * 8 + widx] =
                    (unsigned short)f2bfbits(acc2[j]);
            }
        }
    } else {
        // bias: S16 = sum_{p<16} B^p, B16 = B^16
        const int a = bid - 68;
        const float* Bmat = Bg + a * 4096;
        for (int i = t; i < 4096; i += 512) {
            const int row = i >> 6, col = i & 63;
            buf[0][row * FS + col] = Bmat[i];
            buf[2][row * FS + col] = (row == col) ? 1.f : 0.f;
        }
        __syncthreads();
        int bcur = 0, scur = 2;
        for (int rnd = 0; rnd < 4; ++rnd) {
            mm(buf[scur ^ 1], buf[bcur], buf[scur], buf[scur]);
            mm(buf[bcur ^ 1], buf[bcur], buf[bcur], nullptr);
            __syncthreads();
            scur ^= 1; bcur ^= 1;
        }
        float* vv = Pbuf;
        if (t < 64) {
            float acc = 0.f;
            const float* S16 = buf[scur];
            const float* B16 = buf[bcur];
            for (int q = 0; q < 64; ++q)
                acc += Abg[a * 64 + q] * S16[q * FS + t]
                     + btg[a * 64 + q] * B16[q * FS + t];
            vv[t] = acc;
        }
        __syncthreads();
        if (t < 128) {
            float accb = bog[a * 128 + t];
            const float* UoA = Uog + a * 8192;
            for (int r = 0; r < 64; ++r) accb += vv[r] * UoA[r * 128 + t];
            biasOut[a * 128 + t] = accb;
        }
    }
}
#undef FS

// ---------------------------------------------------------------------------
// Main GEMM: 512 blocks x 512 threads = 8 INDEPENDENT waves (no barrier,
// no LDS). Block tile 128M x 256N; wave (w>>2 -> m-half, w&3 -> n-group)
// owns 64x64. A direct global->frag (f32, cvt in regs); B reg dbuf from Wp.
// Co-location gives L1 reuse: 4 n-waves read identical A lines; (w, w+4)
// pairs read identical B frags.
// ---------------------------------------------------------------------------
__global__ __launch_bounds__(512) void tt_gemm(
    const float* __restrict__ nh,           // (32768,16,128)
    const float* __restrict__ te,           // (32768,128)
    const unsigned short* __restrict__ Wp,  // [34][8][512][8] bf16
    const float* __restrict__ bias,         // [512]
    float* __restrict__ out)                // (32768,512)
{
    const int t = threadIdx.x;
    const int lane = t & 63, w = t >> 6;
    // chunked XCD map: the two n-halves of one 128-row m-tile land on the
    // same XCD (L2-shared A panel).
    const int lt = (blockIdx.x & 7) * 64 + (blockIdx.x >> 3);   // 512 = 8*64
    const int m0 = (lt >> 1) * 128 + (w >> 2) * 64;   // wave's 64-row base
    const int wc = (lt & 1) * 4 + (w & 3);            // n-group 0..7 (x64 cols)
    const int lx = lane & 15, lg = lane >> 4;

    // A fragment source pointers: lane holds row fm*16+lx, k = lg*8 + j.
    const float* ar[4];
    const float* trp[4];
#pragma unroll
    for (int fm = 0; fm < 4; ++fm) {
        ar[fm]  = nh + (size_t)(m0 + fm * 16 + lx) * 2048 + lg * 8;
        trp[fm] = te + (size_t)(m0 + fm * 16 + lx) * 128  + lg * 8;
    }

    // B frag byte base: + kt*65536 + kk*32768 + fn*256  (verified r5-r10)
    const char* const wbase = (const char*)Wp + lg * 8192 + wc * 1024 + lx * 16;

    f32x4 acc[4][4] = {};
    uint4  bF0[4][2], bF1[4][2];   // B frags (distance-1 double buffer)

#define LOADB(dst, kt_) do {                                                   \
    const char* _q = wbase + (size_t)(kt_) * 65536;                            \
    _Pragma("unroll")                                                          \
    for (int _kk = 0; _kk < 2; ++_kk)                                          \
        _Pragma("unroll")                                                      \
        for (int _fn = 0; _fn < 4; ++_fn)                                      \
            dst[_fn][_kk] = *(const uint4*)(_q + _kk * 32768 + _fn * 256);     \
} while (0)

// One K-tile (K=64): per fm load 16 f32 (4x float4), cvt to 2 frags, 8 MFMA.
#define ASTEP(kt_, bsrc) do {                                                  \
    _Pragma("unroll")                                                          \
    for (int _fm = 0; _fm < 4; ++_fm) {                                        \
        const float* _p = ((kt_) < 32) ? (ar[_fm] + (kt_) * 64)                \
                                       : (trp[_fm] + ((kt_) - 32) * 64);       \
        float4 _x0 = *(const float4*)(_p);                                     \
        float4 _x1 = *(const float4*)(_p + 4);                                 \
        float4 _x2 = *(const float4*)(_p + 32);                                \
        float4 _x3 = *(const float4*)(_p + 36);                                \
        uint4 _u0, _u1;                                                        \
        _u0.x = pack2(_x0.x, _x0.y);  _u0.y = pack2(_x0.z, _x0.w);             \
        _u0.z = pack2(_x1.x, _x1.y);  _u0.w = pack2(_x1.z, _x1.w);             \
        _u1.x = pack2(_x2.x, _x2.y);  _u1.y = pack2(_x2.z, _x2.w);             \
        _u1.z = pack2(_x3.x, _x3.y);  _u1.w = pack2(_x3.z, _x3.w);             \
        bf16x8 _a0 = __builtin_bit_cast(bf16x8, _u0);                          \
        bf16x8 _a1 = __builtin_bit_cast(bf16x8, _u1);                          \
        _Pragma("unroll")                                                      \
        for (int _fn = 0; _fn < 4; ++_fn)                                      \
            acc[_fm][_fn] = __builtin_amdgcn_mfma_f32_16x16x32_bf16(           \
                _a0, __builtin_bit_cast(bf16x8, bsrc[_fn][0]),                 \
                acc[_fm][_fn], 0, 0, 0);                                       \
        _Pragma("unroll")                                                      \
        for (int _fn = 0; _fn < 4; ++_fn)                                      \
            acc[_fm][_fn] = __builtin_amdgcn_mfma_f32_16x16x32_bf16(           \
                _a1, __builtin_bit_cast(bf16x8, bsrc[_fn][1]),                 \
                acc[_fm][_fn], 0, 0, 0);                                       \
    }                                                                          \
} while (0)

    LOADB(bF0, 0);
#pragma unroll 1
    for (int kt = 0; kt < 34; kt += 2) {
        LOADB(bF1, kt + 1);            // in flight across ASTEP(kt)
        ASTEP(kt, bF0);
        if (kt + 2 < 34) LOADB(bF0, kt + 2);
        ASTEP(kt + 1, bF1);
    }
#undef ASTEP
#undef LOADB

    // epilogue: C/D layout col = lane&15, row = (lane>>4)*4 + reg  [m89]
    const int orow = m0 + lg * 4;
    const int ocol = wc * 64 + lx;
    float bv[4];
#pragma unroll
    for (int fn = 0; fn < 4; ++fn) bv[fn] = bias[ocol + fn * 16];
#pragma unroll
    for (int fm = 0; fm < 4; ++fm)
#pragma unroll
        for (int fn = 0; fn < 4; ++fn)
#pragma unroll
            for (int j = 0; j < 4; ++j)
                out[(size_t)(orow + fm * 16 + j) * 512 + ocol + fn * 16] =
                    acc[fm][fn][j] + bv[fn];
}

// ---------------------------------------------------------------------------
extern "C" void kernel_launch(void* const* d_in, const int* in_sizes, int n_in,
                              void* d_out, int out_size, void* d_ws, size_t ws_size,
                              hipStream_t stream) {
    const float* nh  = (const float*)d_in[0];
    const float* te  = (const float*)d_in[1];
    const float* Ag  = (const float*)d_in[2];
    const float* Bg  = (const float*)d_in[3];
    const float* Abg = (const float*)d_in[4];
    const float* Utg = (const float*)d_in[5];
    const float* btg = (const float*)d_in[6];
    const float* Uog = (const float*)d_in[7];
    const float* bog = (const float*)d_in[8];

    unsigned short* Wp = (unsigned short*)d_ws;              // 34*8*512*8*2 B
    float* bias = (float*)((char*)d_ws + (size_t)34 * 8 * 512 * 8 * 2);
    float* out = (float*)d_out;

    hipLaunchKernelGGL(tt_fold, dim3(72), dim3(512), 0, stream,
                       Ag, Bg, Abg, Utg, btg, Uog, bog, Wp, bias);
    hipLaunchKernelGGL(tt_gemm, dim3(512), dim3(512), 0, stream,
                       nh, te, Wp, bias, out);
}

// Round 12
// 230.858 us; speedup vs baseline: 1.6581x; 1.6581x over previous
//
#include <hip/hip_runtime.h>
#include <hip/hip_bf16.h>

// TensorTrainLMN: out[b, a*128+h] = X[b,:] @ W[:, a*128+h] + bias
//   X[b] = [nh[b,0,:128], ..., nh[b,15,:128], te[b,:128]]   (K = 2176)
// tt_fold: folds A@B^(15-c)@U_out (exact f32) into W bf16, PRE-PACKED as the
//   GEMM LDS B-tile image: Wp[nblk][kt][slot=(k/8)&7][nloc 256][8 bf16].
// tt_gemm: m201-style 4-phase schedule, de-spilled (no launch-bounds cap):
//   256x256x64 tile, 512 thr (8 waves 2x4, wave 128x64), 128KB LDS dbuf.
//   Per phase: {ds_read frag subtile | stage-issue; s_barrier; lgkm0;
//   setprio1; 16 MFMA; setprio0; s_barrier}. B via global_load_lds (issued
//   phase 0, retired by counted vmcnt(8) at tile end - 3 phases old). A
//   reg-staged f32 (loads issued phase 3, cvt+ds_write at next tile's
//   phases 2/3 -> ~4-phase in-flight distance, compiler-counted waits).

typedef short bf16x8 __attribute__((ext_vector_type(8)));
typedef float f32x4  __attribute__((ext_vector_type(4)));

__device__ __forceinline__ unsigned f2bfbits(float f) {
    unsigned u = __builtin_bit_cast(unsigned, f);
    return (u + 0x7FFFu + ((u >> 16) & 1u)) >> 16;   // round-to-nearest-even
}
// compiler fuses pairs into v_cvt_pk_bf16_f32 (m240)
__device__ __forceinline__ unsigned pack2(float a, float b) {
    unsigned lo = (unsigned)__builtin_bit_cast(unsigned short, __float2bfloat16(a));
    unsigned hi = (unsigned)__builtin_bit_cast(unsigned short, __float2bfloat16(b));
    return lo | (hi << 16);
}

// ---------------------------------------------------------------------------
// Fold kernel: 72 blocks x 512 threads (math verified r2-r11; Wp indexing is
// r4's verified [nblk][kt][slot][nloc][8] tile image).
// ---------------------------------------------------------------------------
#define FS 68   // fold matmul LDS row stride (floats); 16B-aligned, 2-way banks

__global__ __launch_bounds__(512) void tt_fold(
    const float* __restrict__ Ag,    // (4,128,64)
    const float* __restrict__ Bg,    // (4,64,64)
    const float* __restrict__ Abg,   // (4,1,64)
    const float* __restrict__ Utg,   // (4,128,64)
    const float* __restrict__ btg,   // (4,1,64)
    const float* __restrict__ Uog,   // (4,64,128)
    const float* __restrict__ bog,   // (4,1,128)
    unsigned short* __restrict__ Wp, // [2][34][8][256][8] bf16
    float* __restrict__ biasOut)     // [512]
{
    __shared__ __align__(16) float L[23552];   // 92 KB
    const int t = threadIdx.x;
    const int bid = blockIdx.x;

    auto mm = [&](float* d, const float* x, const float* y, const float* add) {
        const int r = t >> 3, c0 = (t & 7) << 3;
        float acc[8];
#pragma unroll
        for (int j = 0; j < 8; ++j) acc[j] = 0.f;
        for (int k = 0; k < 64; ++k) {
            const float a = x[r * FS + k];
            const float4 y0 = *(const float4*)(y + k * FS + c0);
            const float4 y1 = *(const float4*)(y + k * FS + c0 + 4);
            acc[0] += a * y0.x; acc[1] += a * y0.y;
            acc[2] += a * y0.z; acc[3] += a * y0.w;
            acc[4] += a * y1.x; acc[5] += a * y1.y;
            acc[6] += a * y1.z; acc[7] += a * y1.w;
        }
        if (add) {
#pragma unroll
            for (int j = 0; j < 8; ++j) acc[j] += add[r * FS + c0 + j];
        }
#pragma unroll
        for (int j = 0; j < 8; ++j) d[r * FS + c0 + j] = acc[j];
    };

    float* buf[4];
    buf[0] = L;
    buf[1] = L + 4352;
    buf[2] = L + 8704;
    buf[3] = L + 13056;
    float* const Pbuf = L + 17408;   // 64x64 dense (stride 64)
    float* const UC   = L + 21504;   // 16x128 staging

    if (bid < 68) {
        int a, p, kbase;
        const float* src;
        if (bid < 64) { a = bid >> 4; const int c = bid & 15; p = 15 - c; kbase = c * 128; src = Ag  + a * 8192; }
        else          { a = bid - 64; p = 16; kbase = 2048;               src = Utg + a * 8192; }
        const float* Bmat = Bg + a * 4096;

        for (int i = t; i < 4096; i += 512) {
            const int row = i >> 6, col = i & 63;
            buf[0][row * FS + col] = Bmat[i];
            buf[2][row * FS + col] = (row == col) ? 1.f : 0.f;
        }
        __syncthreads();
        int bcur = 0, rcur = 2;
        int e = p;
        while (e) {
            if (e & 1) { mm(buf[rcur ^ 1], buf[rcur], buf[bcur], nullptr); rcur ^= 1; __syncthreads(); }
            e >>= 1;
            if (e)     { mm(buf[bcur ^ 1], buf[bcur], buf[bcur], nullptr); bcur ^= 1; __syncthreads(); }
        }

        {
            const int prow = t >> 3, pc0 = (t & 7) << 3;
#pragma unroll
            for (int j = 0; j < 8; ++j)
                Pbuf[prow * 64 + pc0 + j] = buf[rcur][prow * FS + pc0 + j];
        }
        __syncthreads();

        // M1 = src(128x64) @ P, stored stride-65 at L (bufs dead now)
        float* M1 = L;
        {
            const int i = t >> 2, r0 = (t & 3) << 4;
            float acc[16];
#pragma unroll
            for (int j = 0; j < 16; ++j) acc[j] = 0.f;
            for (int q = 0; q < 64; ++q) {
                const float av = src[i * 64 + q];
                const float4* pr = (const float4*)(Pbuf + q * 64 + r0);
#pragma unroll
                for (int jj = 0; jj < 4; ++jj) {
                    float4 v = pr[jj];
                    acc[4 * jj + 0] += av * v.x;
                    acc[4 * jj + 1] += av * v.y;
                    acc[4 * jj + 2] += av * v.z;
                    acc[4 * jj + 3] += av * v.w;
                }
            }
#pragma unroll
            for (int j = 0; j < 16; ++j) M1[i * 65 + r0 + j] = acc[j];
        }
        __syncthreads();

        // W2 = M1(128x64) @ Uo(64x128); Uo staged 16 rows/chunk
        const float* UoA = Uog + a * 8192;
        const int i = t >> 2, h0 = (t & 3) << 5;
        float acc2[32];
#pragma unroll
        for (int j = 0; j < 32; ++j) acc2[j] = 0.f;
        for (int ch = 0; ch < 4; ++ch) {
            __syncthreads();
            for (int idx = t; idx < 2048; idx += 512) UC[idx] = UoA[ch * 2048 + idx];
            __syncthreads();
            for (int rr = 0; rr < 16; ++rr) {
                const float m = M1[i * 65 + ch * 16 + rr];
                const float4* ur = (const float4*)(UC + rr * 128 + h0);
#pragma unroll
                for (int jj = 0; jj < 8; ++jj) {
                    float4 v = ur[jj];
                    acc2[4 * jj + 0] += m * v.x;
                    acc2[4 * jj + 1] += m * v.y;
                    acc2[4 * jj + 2] += m * v.z;
                    acc2[4 * jj + 3] += m * v.w;
                }
            }
        }
        // write pre-packed tile image: [nblk][kt][slot][nloc][8]
        {
            const int k = kbase + i;
            const int kt = k >> 6, slot = (k >> 3) & 7, widx = k & 7;
#pragma unroll
            for (int j = 0; j < 32; ++j) {
                const int n = a * 128 + h0 + j;
                const int n_blk = n >> 8, n_loc = n & 255;
                Wp[((size_t)(n_blk * 34 + kt) * 8 + slot) * 2048 + n_loc * 8 + widx] =
                    (unsigned short)f2bfbits(acc2[j]);
            }
        }
    } else {
        // bias: S16 = sum_{p<16} B^p, B16 = B^16
        const int a = bid - 68;
        const float* Bmat = Bg + a * 4096;
        for (int i = t; i < 4096; i += 512) {
            const int row = i >> 6, col = i & 63;
            buf[0][row * FS + col] = Bmat[i];
            buf[2][row * FS + col] = (row == col) ? 1.f : 0.f;
        }
        __syncthreads();
        int bcur = 0, scur = 2;
        for (int rnd = 0; rnd < 4; ++rnd) {
            mm(buf[scur ^ 1], buf[bcur], buf[scur], buf[scur]);
            mm(buf[bcur ^ 1], buf[bcur], buf[bcur], nullptr);
            __syncthreads();
            scur ^= 1; bcur ^= 1;
        }
        float* vv = Pbuf;
        if (t < 64) {
            float acc = 0.f;
            const float* S16 = buf[scur];
            const float* B16 = buf[bcur];
            for (int q = 0; q < 64; ++q)
                acc += Abg[a * 64 + q] * S16[q * FS + t]
                     + btg[a * 64 + q] * B16[q * FS + t];
            vv[t] = acc;
        }
        __syncthreads();
        if (t < 128) {
            float accb = bog[a * 128 + t];
            const float* UoA = Uog + a * 8192;
            for (int r = 0; r < 64; ++r) accb += vv[r] * UoA[r * 128 + t];
            biasOut[a * 128 + t] = accb;
        }
    }
}
#undef FS

// ---------------------------------------------------------------------------
// Main GEMM: 256 blocks x 512 threads (8 waves 2x4), tile 256x256x64,
// wave 128x64, 34 K-tiles, 128 KB LDS (A 2x32K @0, B 2x32K @64K).
// LDS layouts (both): [buf][kk(2)][slot(4)][idx 256][16B] - conflict-free.
// ---------------------------------------------------------------------------
__global__ __launch_bounds__(512) void tt_gemm(
    const float* __restrict__ nh,           // (32768,16,128)
    const float* __restrict__ te,           // (32768,128)
    const unsigned short* __restrict__ Wp,  // [2][34][8][256][8] bf16
    const float* __restrict__ bias,         // [512]
    float* __restrict__ out)                // (32768,512)
{
    __shared__ __align__(16) char Lds[131072];

    const int t = threadIdx.x;
    const int lane = t & 63, w = t >> 6;
    // chunked XCD map: both n-halves of an m-panel on one XCD (L2 A reuse)
    const int lt = (blockIdx.x & 7) * 32 + (blockIdx.x >> 3);   // 256 = 8*32
    const int m0 = (lt >> 1) * 256;
    const int nblk = lt & 1;
    const int wr = w >> 2, wc = w & 3;           // 2(M) x 4(N) wave grid
    const int lx = lane & 15, lg = lane >> 4;

    // A staging: thread -> row r (0..255), k-half h (32 f32)
    const int r = t >> 1, h = t & 1;
    const float* nhp = nh + (size_t)(m0 + r) * 2048 + h * 32;
    const float* tep = te + (size_t)(m0 + r) * 128  + h * 32;

    char* const Abase = Lds;             // + buf*32768 + (kk*4+sl)*4096 + idx*16
    char* const Bbase = Lds + 65536;
    const int awoff = h * 16384 + r * 16;      // + g*4096 (g=slot), + buf*32768

    // B staging source: per-lane global byte address (linear 32KB/tile image)
    const char* const wsrc = (const char*)Wp + (size_t)nblk * 34 * 32768
                             + w * 1024 + lane * 16;   // + kt*32768 + j*8192

    // frag read bases (within buffer)
    const int aro = (wr * 128 + lx) * 16;    // + (kk*4+lg)*4096 + fm*256
    const int bro = (wc * 64 + lx) * 16;     // + (kk*4+lg)*4096 + fn*256

    f32x4 acc[8][4] = {};
    float4 va[8];                   // A stage regs (one tile, 32 f32)
    bf16x8 aF[4], bF0[4], bF1[4];

#define BAR()   __builtin_amdgcn_s_barrier()
#define LGKM0() asm volatile("s_waitcnt lgkmcnt(0)" ::: "memory")
#define PRIO(x) __builtin_amdgcn_s_setprio(x)

#define GLOADB(buf_, kt_) do {                                                 \
    const char* _gs = wsrc + (size_t)(kt_) * 32768;                            \
    char* _ld = Bbase + (buf_) * 32768 + w * 1024;                             \
    _Pragma("unroll")                                                          \
    for (int _j = 0; _j < 4; ++_j)                                             \
        __builtin_amdgcn_global_load_lds(                                      \
            (const __attribute__((address_space(1))) unsigned int*)(_gs + _j * 8192), \
            (__attribute__((address_space(3))) unsigned int*)(_ld + _j * 8192),\
            16, 0, 0);                                                         \
} while (0)

#define LOADA(kt_) do {                                                        \
    const float* _p = ((kt_) < 32) ? (nhp + (kt_) * 64) : (tep + ((kt_) - 32) * 64); \
    _Pragma("unroll")                                                          \
    for (int _j = 0; _j < 8; ++_j) va[_j] = *(const float4*)(_p + 4 * _j);     \
} while (0)

#define WRITEA_H(buf_, g0) do {                                                \
    _Pragma("unroll")                                                          \
    for (int _g = (g0); _g < (g0) + 2; ++_g) {                                 \
        uint4 _w;                                                              \
        _w.x = pack2(va[2 * _g].x,     va[2 * _g].y);                          \
        _w.y = pack2(va[2 * _g].z,     va[2 * _g].w);                          \
        _w.z = pack2(va[2 * _g + 1].x, va[2 * _g + 1].y);                      \
        _w.w = pack2(va[2 * _g + 1].z, va[2 * _g + 1].w);                      \
        *(uint4*)(Abase + (buf_) * 32768 + awoff + _g * 4096) = _w;            \
    }                                                                          \
} while (0)

#define READA(buf_, kk_, fb_) do {                                             \
    _Pragma("unroll")                                                          \
    for (int _fm = 0; _fm < 4; ++_fm)                                          \
        aF[_fm] = *(const bf16x8*)(Abase + (buf_) * 32768 +                    \
            ((kk_) * 4 + lg) * 4096 + aro + ((fb_) + _fm) * 256);              \
} while (0)

#define READB(dst, buf_, kk_) do {                                             \
    _Pragma("unroll")                                                          \
    for (int _fn = 0; _fn < 4; ++_fn)                                          \
        dst[_fn] = *(const bf16x8*)(Bbase + (buf_) * 32768 +                   \
            ((kk_) * 4 + lg) * 4096 + bro + _fn * 256);                        \
} while (0)

#define MFMA16(fb_, bsrc) do {                                                 \
    _Pragma("unroll")                                                          \
    for (int _fm = 0; _fm < 4; ++_fm)                                          \
        _Pragma("unroll")                                                      \
        for (int _fn = 0; _fn < 4; ++_fn)                                      \
            acc[(fb_) + _fm][_fn] = __builtin_amdgcn_mfma_f32_16x16x32_bf16(   \
                aF[_fm], bsrc[_fn], acc[(fb_) + _fm][_fn], 0, 0, 0);           \
} while (0)

    // ---- prologue: tile 0 -> buf0; va <- tile 1 ----
    GLOADB(0, 0);
    LOADA(0);
    WRITEA_H(0, 0);
    WRITEA_H(0, 2);
    LOADA(1);
    asm volatile("s_waitcnt vmcnt(0) lgkmcnt(0)" ::: "memory");
    BAR();

#pragma unroll 1
    for (int kt = 0; kt < 34; ++kt) {
        const int d = kt & 1;
        const bool stg = (kt + 1) < 34;      // stage tile kt+1 this iter
        const bool lda = (kt + 2) < 34;      // issue A loads for tile kt+2

        // ---- phase 0: kk0, fm0-3 ----
        if (stg) GLOADB(d ^ 1, kt + 1);
        READB(bF0, d, 0);
        READA(d, 0, 0);
        BAR(); LGKM0(); PRIO(1);
        MFMA16(0, bF0);
        PRIO(0); BAR();

        // ---- phase 1: kk0, fm4-7 ----
        READA(d, 0, 4);
        BAR(); LGKM0(); PRIO(1);
        MFMA16(4, bF0);
        PRIO(0); BAR();

        // ---- phase 2: kk1, fm0-3 (+ A write half 0) ----
        READB(bF1, d, 1);
        READA(d, 1, 0);
        if (stg) WRITEA_H(d ^ 1, 0);         // consumes va (tile kt+1)
        BAR(); LGKM0(); PRIO(1);
        MFMA16(0, bF1);
        PRIO(0); BAR();

        // ---- phase 3: kk1, fm4-7 (+ A write half 1, issue A(kt+2)) ----
        READA(d, 1, 4);
        if (stg) WRITEA_H(d ^ 1, 2);
        if (lda) LOADA(kt + 2);              // newest 8 vmem ops
        BAR(); LGKM0(); PRIO(1);
        MFMA16(4, bF1);
        PRIO(0);
        // counted: retire B gloads (3 phases old); A loads stay in flight
        asm volatile("s_waitcnt vmcnt(8)" ::: "memory");
        BAR();
    }

#undef MFMA16
#undef READB
#undef READA
#undef WRITEA_H
#undef LOADA
#undef GLOADB
#undef PRIO
#undef LGKM0
#undef BAR

    // epilogue: C/D layout col = lane&15, row = (lane>>4)*4 + reg  [m89]
    const int orow = m0 + wr * 128 + lg * 4;
    const int ocol = nblk * 256 + wc * 64 + lx;
    float bv[4];
#pragma unroll
    for (int fn = 0; fn < 4; ++fn) bv[fn] = bias[ocol + fn * 16];
#pragma unroll
    for (int fm = 0; fm < 8; ++fm)
#pragma unroll
        for (int fn = 0; fn < 4; ++fn)
#pragma unroll
            for (int j = 0; j < 4; ++j)
                out[(size_t)(orow + fm * 16 + j) * 512 + ocol + fn * 16] =
                    acc[fm][fn][j] + bv[fn];
}

// ---------------------------------------------------------------------------
extern "C" void kernel_launch(void* const* d_in, const int* in_sizes, int n_in,
                              void* d_out, int out_size, void* d_ws, size_t ws_size,
                              hipStream_t stream) {
    const float* nh  = (const float*)d_in[0];
    const float* te  = (const float*)d_in[1];
    const float* Ag  = (const float*)d_in[2];
    const float* Bg  = (const float*)d_in[3];
    const float* Abg = (const float*)d_in[4];
    const float* Utg = (const float*)d_in[5];
    const float* btg = (const float*)d_in[6];
    const float* Uog = (const float*)d_in[7];
    const float* bog = (const float*)d_in[8];

    unsigned short* Wp = (unsigned short*)d_ws;              // 2*34*32768 B
    float* bias = (float*)((char*)d_ws + (size_t)2 * 34 * 32768);
    float* out = (float*)d_out;

    hipLaunchKernelGGL(tt_fold, dim3(72), dim3(512), 0, stream,
                       Ag, Bg, Abg, Utg, btg, Uog, bog, Wp, bias);
    hipLaunchKernelGGL(tt_gemm, dim3(256), dim3(512), 0, stream,
                       nh, te, Wp, bias, out);
}

// Round 13
// 195.983 us; speedup vs baseline: 1.9532x; 1.1779x over previous
//
#include <hip/hip_runtime.h>
#include <hip/hip_bf16.h>

// TensorTrainLMN: out[b, a*128+h] = X[b,:] @ W[:, a*128+h] + bias
//   X[b] = [nh[b,0,:128], ..., nh[b,15,:128], te[b,:128]]   (K = 2176)
//
// tt_prep (grid 2120 x 512): blocks 0-67 fold W into Bp[nb4][kt34][slot8]
//   [nloc128][8] bf16; 68-71 bias; 72+ convert nh/te f32 -> bf16 pre-tiled
//   Ap[mt256][kt34][slot8][row128][8] (the GEMM's exact LDS staging image).
// tt_gemm (fast): m97-clone. 128x128 tile, 4 waves (64x64), BK=32, BOTH
//   operands via global_load_lds (no staging VGPRs -> ~110 total regs ->
//   4 waves/SIMD bucket), 3-slot LDS ring (48KB -> 3 blocks/CU), distance-2
//   DMA, fused "vmcnt(N); s_barrier" asm (wave retires its own DMA before
//   the publishing barrier; newest 4 stay in flight).
// Fallback (ws too small for Ap): r10-structure gemm reading f32 nh.

typedef short bf16x8 __attribute__((ext_vector_type(8)));
typedef float f32x4  __attribute__((ext_vector_type(4)));

__device__ __forceinline__ unsigned f2bfbits(float f) {
    unsigned u = __builtin_bit_cast(unsigned, f);
    return (u + 0x7FFFu + ((u >> 16) & 1u)) >> 16;   // round-to-nearest-even
}
__device__ __forceinline__ unsigned pack2(float a, float b) {
    unsigned lo = (unsigned)__builtin_bit_cast(unsigned short, __float2bfloat16(a));
    unsigned hi = (unsigned)__builtin_bit_cast(unsigned short, __float2bfloat16(b));
    return lo | (hi << 16);
}

// ---------------------------------------------------------------------------
// Prep kernel: fold (bid<68), bias (68-71), cvt (72+).
// ---------------------------------------------------------------------------
#define FS 68

__global__ __launch_bounds__(512) void tt_prep(
    const float* __restrict__ nh,    // (32768,16,128)
    const float* __restrict__ te,    // (32768,128)
    const float* __restrict__ Ag,    // (4,128,64)
    const float* __restrict__ Bg,    // (4,64,64)
    const float* __restrict__ Abg,   // (4,1,64)
    const float* __restrict__ Utg,   // (4,128,64)
    const float* __restrict__ btg,   // (4,1,64)
    const float* __restrict__ Uog,   // (4,64,128)
    const float* __restrict__ bog,   // (4,1,128)
    unsigned short* __restrict__ Bp, // [4][34][8][128][8] bf16
    float* __restrict__ biasOut,     // [512]
    unsigned short* __restrict__ Ap) // [256][34][8][128][8] bf16
{
    __shared__ __align__(16) float L[23552];   // 92 KB (fold blocks only)
    const int t = threadIdx.x;
    const int bid = blockIdx.x;

    if (bid >= 72) {
        // ---- cvt: nh/te -> Ap tiled bf16 image ----
        const int cb = bid - 72;          // 0..2047
        const int mt = cb >> 3;
        const int r = t >> 2, q = t & 3;  // row 0..127, k-quarter (16 f32)
        for (int kt = cb & 7; kt < 34; kt += 8) {
            const float* src = (kt < 32)
                ? nh + ((size_t)(mt * 128 + r) * 2048 + kt * 64 + q * 16)
                : te + ((size_t)(mt * 128 + r) * 128 + (kt - 32) * 64 + q * 16);
            float4 v0 = ((const float4*)src)[0];
            float4 v1 = ((const float4*)src)[1];
            float4 v2 = ((const float4*)src)[2];
            float4 v3 = ((const float4*)src)[3];
            uint4 w0, w1;
            w0.x = pack2(v0.x, v0.y);  w0.y = pack2(v0.z, v0.w);
            w0.z = pack2(v1.x, v1.y);  w0.w = pack2(v1.z, v1.w);
            w1.x = pack2(v2.x, v2.y);  w1.y = pack2(v2.z, v2.w);
            w1.z = pack2(v3.x, v3.y);  w1.w = pack2(v3.z, v3.w);
            unsigned short* dst = Ap + (size_t)(mt * 34 + kt) * 8192;
            *(uint4*)(dst + (2 * q)     * 1024 + r * 8) = w0;  // slot 2q
            *(uint4*)(dst + (2 * q + 1) * 1024 + r * 8) = w1;  // slot 2q+1
        }
        return;
    }

    auto mm = [&](float* d, const float* x, const float* y, const float* add) {
        const int r = t >> 3, c0 = (t & 7) << 3;
        float acc[8];
#pragma unroll
        for (int j = 0; j < 8; ++j) acc[j] = 0.f;
        for (int k = 0; k < 64; ++k) {
            const float a = x[r * FS + k];
            const float4 y0 = *(const float4*)(y + k * FS + c0);
            const float4 y1 = *(const float4*)(y + k * FS + c0 + 4);
            acc[0] += a * y0.x; acc[1] += a * y0.y;
            acc[2] += a * y0.z; acc[3] += a * y0.w;
            acc[4] += a * y1.x; acc[5] += a * y1.y;
            acc[6] += a * y1.z; acc[7] += a * y1.w;
        }
        if (add) {
#pragma unroll
            for (int j = 0; j < 8; ++j) acc[j] += add[r * FS + c0 + j];
        }
#pragma unroll
        for (int j = 0; j < 8; ++j) d[r * FS + c0 + j] = acc[j];
    };

    float* buf[4];
    buf[0] = L;
    buf[1] = L + 4352;
    buf[2] = L + 8704;
    buf[3] = L + 13056;
    float* const Pbuf = L + 17408;   // 64x64 dense (stride 64)
    float* const UC   = L + 21504;   // 16x128 staging

    if (bid < 68) {
        int a, p, kbase;
        const float* src;
        if (bid < 64) { a = bid >> 4; const int c = bid & 15; p = 15 - c; kbase = c * 128; src = Ag  + a * 8192; }
        else          { a = bid - 64; p = 16; kbase = 2048;               src = Utg + a * 8192; }
        const float* Bmat = Bg + a * 4096;

        for (int i = t; i < 4096; i += 512) {
            const int row = i >> 6, col = i & 63;
            buf[0][row * FS + col] = Bmat[i];
            buf[2][row * FS + col] = (row == col) ? 1.f : 0.f;
        }
        __syncthreads();
        int bcur = 0, rcur = 2;
        int e = p;
        while (e) {
            if (e & 1) { mm(buf[rcur ^ 1], buf[rcur], buf[bcur], nullptr); rcur ^= 1; __syncthreads(); }
            e >>= 1;
            if (e)     { mm(buf[bcur ^ 1], buf[bcur], buf[bcur], nullptr); bcur ^= 1; __syncthreads(); }
        }

        {
            const int prow = t >> 3, pc0 = (t & 7) << 3;
#pragma unroll
            for (int j = 0; j < 8; ++j)
                Pbuf[prow * 64 + pc0 + j] = buf[rcur][prow * FS + pc0 + j];
        }
        __syncthreads();

        // M1 = src(128x64) @ P, stored stride-65 at L
        float* M1 = L;
        {
            const int i = t >> 2, r0 = (t & 3) << 4;
            float acc[16];
#pragma unroll
            for (int j = 0; j < 16; ++j) acc[j] = 0.f;
            for (int q = 0; q < 64; ++q) {
                const float av = src[i * 64 + q];
                const float4* pr = (const float4*)(Pbuf + q * 64 + r0);
#pragma unroll
                for (int jj = 0; jj < 4; ++jj) {
                    float4 v = pr[jj];
                    acc[4 * jj + 0] += av * v.x;
                    acc[4 * jj + 1] += av * v.y;
                    acc[4 * jj + 2] += av * v.z;
                    acc[4 * jj + 3] += av * v.w;
                }
            }
#pragma unroll
            for (int j = 0; j < 16; ++j) M1[i * 65 + r0 + j] = acc[j];
        }
        __syncthreads();

        // W2 = M1(128x64) @ Uo(64x128)
        const float* UoA = Uog + a * 8192;
        const int i = t >> 2, h0 = (t & 3) << 5;
        float acc2[32];
#pragma unroll
        for (int j = 0; j < 32; ++j) acc2[j] = 0.f;
        for (int ch = 0; ch < 4; ++ch) {
            __syncthreads();
            for (int idx = t; idx < 2048; idx += 512) UC[idx] = UoA[ch * 2048 + idx];
            __syncthreads();
            for (int rr = 0; rr < 16; ++rr) {
                const float m = M1[i * 65 + ch * 16 + rr];
                const float4* ur = (const float4*)(UC + rr * 128 + h0);
#pragma unroll
                for (int jj = 0; jj < 8; ++jj) {
                    float4 v = ur[jj];
                    acc2[4 * jj + 0] += m * v.x;
                    acc2[4 * jj + 1] += m * v.y;
                    acc2[4 * jj + 2] += m * v.z;
                    acc2[4 * jj + 3] += m * v.w;
                }
            }
        }
        // write Bp image: [nb = n>>7][kt][slot][nloc = n&127][8]
        {
            const int k = kbase + i;
            const int kt = k >> 6, slot = (k >> 3) & 7, widx = k & 7;
#pragma unroll
            for (int j = 0; j < 32; ++j) {
                const int n = a * 128 + h0 + j;
                Bp[((size_t)(((n >> 7) * 34 + kt) * 8 + slot)) * 1024 + (n & 127) * 8 + widx] =
                    (unsigned short)f2bfbits(acc2[j]);
            }
        }
    } else {
        // bias: S16 = sum_{p<16} B^p, B16 = B^16
        const int a = bid - 68;
        const float* Bmat = Bg + a * 4096;
        for (int i = t; i < 4096; i += 512) {
            const int row = i >> 6, col = i & 63;
            buf[0][row * FS + col] = Bmat[i];
            buf[2][row * FS + col] = (row == col) ? 1.f : 0.f;
        }
        __syncthreads();
        int bcur = 0, scur = 2;
        for (int rnd = 0; rnd < 4; ++rnd) {
            mm(buf[scur ^ 1], buf[bcur], buf[scur], buf[scur]);
            mm(buf[bcur ^ 1], buf[bcur], buf[bcur], nullptr);
            __syncthreads();
            scur ^= 1; bcur ^= 1;
        }
        float* vv = Pbuf;
        if (t < 64) {
            float acc = 0.f;
            const float* S16 = buf[scur];
            const float* B16 = buf[bcur];
            for (int q = 0; q < 64; ++q)
                acc += Abg[a * 64 + q] * S16[q * FS + t]
                     + btg[a * 64 + q] * B16[q * FS + t];
            vv[t] = acc;
        }
        __syncthreads();
        if (t < 128) {
            float accb = bog[a * 128 + t];
            const float* UoA = Uog + a * 8192;
            for (int r = 0; r < 64; ++r) accb += vv[r] * UoA[r * 128 + t];
            biasOut[a * 128 + t] = accb;
        }
    }
}
#undef FS

// fused wait+barrier: memory clobber fences both sides (reads can't hoist
// above the barrier, DMA issues can't sink below).
#define WAITBAR(NSTR) \
    asm volatile("s_waitcnt vmcnt(" NSTR ")\n\ts_barrier" ::: "memory")

// ---------------------------------------------------------------------------
// Fast GEMM: 1024 blocks x 256 thr (4 waves 2x2), tile 128x128, wave 64x64,
// BK=32 (68 steps). Both operands via global_load_lds from pre-tiled bf16
// images. 3-slot LDS ring (3 x 16KB), DMA distance-2, vmcnt(4) steady.
// ---------------------------------------------------------------------------
__global__ __launch_bounds__(256) void tt_gemm(
    const unsigned short* __restrict__ Ap,  // [256][34][8][128][8]
    const unsigned short* __restrict__ Bp,  // [4][34][8][128][8]
    const float* __restrict__ bias,         // [512]
    float* __restrict__ out)                // (32768,512)
{
    __shared__ __align__(16) char Lds[49152];   // 3 x (A 8KB | B 8KB)

    const int t = threadIdx.x;
    const int lane = t & 63, w = t >> 6;
    // chunked XCD map: 4 consecutive lt share one mt (A panel L2-shared)
    const int lt = (blockIdx.x & 7) * 128 + (blockIdx.x >> 3);  // 1024 = 8*128
    const int mt = lt >> 2, nb = lt & 3;
    const int wr = w >> 1, wc = w & 1;
    const int lx = lane & 15, lg = lane >> 4;

    // staging source (per-lane): step s adds s*8192 bytes (contiguous halves)
    const char* const asrc = (const char*)Ap + (size_t)mt * 557056 + w * 2048 + lane * 16;
    const char* const bsrc = (const char*)Bp + (size_t)nb * 557056 + w * 2048 + lane * 16;

    // frag read offsets within a ring slot
    const int aro = lg * 2048 + (wr * 64 + lx) * 16;   // + fm*256
    const int bro = lg * 2048 + (wc * 64 + lx) * 16;   // + fn*256

    f32x4 acc[4][4] = {};

#define STAGE(slot_, s_) do {                                                  \
    const char* _ga = asrc + (size_t)(s_) * 8192;                              \
    const char* _gb = bsrc + (size_t)(s_) * 8192;                              \
    char* _ld = Lds + (slot_) * 16384 + w * 2048;                              \
    _Pragma("unroll")                                                          \
    for (int _j = 0; _j < 2; ++_j)                                             \
        __builtin_amdgcn_global_load_lds(                                      \
            (const __attribute__((address_space(1))) unsigned int*)(_ga + _j * 1024), \
            (__attribute__((address_space(3))) unsigned int*)(_ld + _j * 1024),\
            16, 0, 0);                                                         \
    _Pragma("unroll")                                                          \
    for (int _j = 0; _j < 2; ++_j)                                             \
        __builtin_amdgcn_global_load_lds(                                      \
            (const __attribute__((address_space(1))) unsigned int*)(_gb + _j * 1024), \
            (__attribute__((address_space(3))) unsigned int*)(_ld + 8192 + _j * 1024), \
            16, 0, 0);                                                         \
} while (0)

    // prologue: slots 0,1 staged; retire slot 0, publish.
    STAGE(0, 0);
    STAGE(1, 1);
    WAITBAR("4");

    int cur = 0;                      // ring slot of step s
#pragma unroll 1
    for (int s = 0; s < 68; ++s) {
        const int nxt2 = (cur >= 1) ? cur - 1 : cur + 2;   // (s+2) % 3
        if (s + 2 < 68) STAGE(nxt2, s + 2);

        const char* Ab = Lds + cur * 16384;
        bf16x8 aF[4], bF[4];
#pragma unroll
        for (int f = 0; f < 4; ++f) {
            aF[f] = *(const bf16x8*)(Ab + aro + f * 256);
            bF[f] = *(const bf16x8*)(Ab + 8192 + bro + f * 256);
        }
#pragma unroll
        for (int fm = 0; fm < 4; ++fm)
#pragma unroll
            for (int fn = 0; fn < 4; ++fn)
                acc[fm][fn] = __builtin_amdgcn_mfma_f32_16x16x32_bf16(
                    aF[fm], bF[fn], acc[fm][fn], 0, 0, 0);

        // retire stage(s+1) before the barrier that publishes it;
        // stage(s+2)'s 4 ops stay in flight.
        if (s + 2 < 68)      WAITBAR("4");
        else if (s + 1 < 68) WAITBAR("0");   // s == 66
        // s == 67: done, no barrier needed
        cur = (cur == 2) ? 0 : cur + 1;
    }
#undef STAGE

    // epilogue: C/D layout col = lane&15, row = (lane>>4)*4 + reg  [m89]
    const int orow = mt * 128 + wr * 64 + lg * 4;
    const int ocol = nb * 128 + wc * 64 + lx;
    float bv[4];
#pragma unroll
    for (int fn = 0; fn < 4; ++fn) bv[fn] = bias[ocol + fn * 16];
#pragma unroll
    for (int fm = 0; fm < 4; ++fm)
#pragma unroll
        for (int fn = 0; fn < 4; ++fn)
#pragma unroll
            for (int j = 0; j < 4; ++j)
                out[(size_t)(orow + fm * 16 + j) * 512 + ocol + fn * 16] =
                    acc[fm][fn][j] + bv[fn];
}

// ---------------------------------------------------------------------------
// Fallback GEMM (ws too small for Ap): r10 structure, f32 nh direct,
// B from the new Bp layout. 1024 blocks x 256 thr.
// ---------------------------------------------------------------------------
#define SYNC_NODRAIN() do {                                   \
    asm volatile("s_waitcnt lgkmcnt(0)" ::: "memory");        \
    __builtin_amdgcn_s_barrier();                             \
} while (0)

__global__ __launch_bounds__(256) void tt_gemm_fb(
    const float* __restrict__ nh,
    const float* __restrict__ te,
    const unsigned short* __restrict__ Bp,  // [4][34][8][128][8]
    const float* __restrict__ bias,
    float* __restrict__ out)
{
    __shared__ __align__(16) char Ab[16384];

    const int t = threadIdx.x;
    const int lane = t & 63, wave = t >> 6;
    const int lt = (blockIdx.x & 7) * 128 + (blockIdx.x >> 3);
    const int m0 = (lt >> 1) * 64;
    const int wc = (lt & 1) * 4 + wave;          // n-group 0..7
    const int lx = lane & 15, lg = lane >> 4;

    const int r = t >> 2, c = t & 3;
    const float* nhp = nh + (size_t)(m0 + r) * 2048 + c * 16;
    const float* tep = te + (size_t)(m0 + r) * 128  + c * 16;
    const int awoff = (c >> 1) * 4096 + (c & 1) * 2048 + r * 16;
    const int aroff = lg * 1024 + lx * 16;

    // B byte base in new layout: + kt*16384 + (kk*4+lg)*2048 + fn*256
    const char* const wbase = (const char*)Bp + (size_t)(wc >> 1) * 557056
                              + ((wc & 1) * 64 + lx) * 16 + lg * 2048;

    f32x4 acc[4][4] = {};
    float4 va0[4], va1[4];
    uint4  bF0[4][2], bF1[4][2];

#define LOADA(dst, kt_) do {                                                   \
    const float* _p = ((kt_) < 32) ? (nhp + (kt_) * 64) : (tep + ((kt_) - 32) * 64); \
    _Pragma("unroll")                                                          \
    for (int _j = 0; _j < 4; ++_j) dst[_j] = *(const float4*)(_p + 4 * _j);    \
} while (0)

#define WRITEA(src, d_) do {                                                   \
    uint4 _w0, _w1;                                                            \
    _w0.x = pack2(src[0].x, src[0].y);  _w0.y = pack2(src[0].z, src[0].w);     \
    _w0.z = pack2(src[1].x, src[1].y);  _w0.w = pack2(src[1].z, src[1].w);     \
    _w1.x = pack2(src[2].x, src[2].y);  _w1.y = pack2(src[2].z, src[2].w);     \
    _w1.z = pack2(src[3].x, src[3].y);  _w1.w = pack2(src[3].z, src[3].w);     \
    *(uint4*)(Ab + (d_) * 8192 + awoff)        = _w0;                          \
    *(uint4*)(Ab + (d_) * 8192 + awoff + 1024) = _w1;                          \
} while (0)

#define LOADB(dst, kt_) do {                                                   \
    const char* _q = wbase + (size_t)(kt_) * 16384;                            \
    _Pragma("unroll")                                                          \
    for (int _kk = 0; _kk < 2; ++_kk)                                          \
        _Pragma("unroll")                                                      \
        for (int _fn = 0; _fn < 4; ++_fn)                                      \
            dst[_fn][_kk] = *(const uint4*)(_q + _kk * 8192 + _fn * 256);      \
} while (0)

#define COMPUTE(d_, bsrc) do {                                                 \
    _Pragma("unroll")                                                          \
    for (int _kk = 0; _kk < 2; ++_kk) {                                        \
        bf16x8 _aF[4];                                                         \
        _Pragma("unroll")                                                      \
        for (int _fm = 0; _fm < 4; ++_fm)                                      \
            _aF[_fm] = *(const bf16x8*)(Ab + (d_) * 8192 + _kk * 4096 + aroff + _fm * 256); \
        _Pragma("unroll")                                                      \
        for (int _fm = 0; _fm < 4; ++_fm)                                      \
            _Pragma("unroll")                                                  \
            for (int _fn = 0; _fn < 4; ++_fn)                                  \
                acc[_fm][_fn] = __builtin_amdgcn_mfma_f32_16x16x32_bf16(       \
                    _aF[_fm], __builtin_bit_cast(bf16x8, bsrc[_fn][_kk]),      \
                    acc[_fm][_fn], 0, 0, 0);                                   \
    }                                                                          \
} while (0)

    LOADA(va0, 0);
    WRITEA(va0, 0);
    LOADA(va1, 1);
    LOADA(va0, 2);
    LOADB(bF0, 0);
    LOADB(bF1, 1);
    SYNC_NODRAIN();

#pragma unroll 1
    for (int kt = 0; kt < 34; kt += 2) {
        WRITEA(va1, 1);
        if (kt + 3 < 34) LOADA(va1, kt + 3);
        COMPUTE(0, bF0);
        if (kt + 2 < 34) LOADB(bF0, kt + 2);
        SYNC_NODRAIN();

        if (kt + 2 < 34) {
            WRITEA(va0, 0);
            if (kt + 4 < 34) LOADA(va0, kt + 4);
        }
        COMPUTE(1, bF1);
        if (kt + 3 < 34) LOADB(bF1, kt + 3);
        SYNC_NODRAIN();
    }
#undef LOADA
#undef WRITEA
#undef LOADB
#undef COMPUTE

    const int orow = m0 + lg * 4;
    const int ocol = wc * 64 + lx;
    float bv[4];
#pragma unroll
    for (int fn = 0; fn < 4; ++fn) bv[fn] = bias[ocol + fn * 16];
#pragma unroll
    for (int fm = 0; fm < 4; ++fm)
#pragma unroll
        for (int fn = 0; fn < 4; ++fn)
#pragma unroll
            for (int j = 0; j < 4; ++j)
                out[(size_t)(orow + fm * 16 + j) * 512 + ocol + fn * 16] =
                    acc[fm][fn][j] + bv[fn];
}

// ---------------------------------------------------------------------------
extern "C" void kernel_launch(void* const* d_in, const int* in_sizes, int n_in,
                              void* d_out, int out_size, void* d_ws, size_t ws_size,
                              hipStream_t stream) {
    const float* nh  = (const float*)d_in[0];
    const float* te  = (const float*)d_in[1];
    const float* Ag  = (const float*)d_in[2];
    const float* Bg  = (const float*)d_in[3];
    const float* Abg = (const float*)d_in[4];
    const float* Utg = (const float*)d_in[5];
    const float* btg = (const float*)d_in[6];
    const float* Uog = (const float*)d_in[7];
    const float* bog = (const float*)d_in[8];

    unsigned short* Bp = (unsigned short*)d_ws;               // 2,228,224 B
    float* bias = (float*)((char*)d_ws + 2228224);            // 2,048 B
    unsigned short* Ap = (unsigned short*)((char*)d_ws + 2230272); // 142.6 MB
    float* out = (float*)d_out;

    const bool fast = ws_size >= (size_t)144836608;

    if (fast) {
        hipLaunchKernelGGL(tt_prep, dim3(72 + 2048), dim3(512), 0, stream,
                           nh, te, Ag, Bg, Abg, Utg, btg, Uog, bog, Bp, bias, Ap);
        hipLaunchKernelGGL(tt_gemm, dim3(1024), dim3(256), 0, stream,
                           Ap, Bp, bias, out);
    } else {
        hipLaunchKernelGGL(tt_prep, dim3(72), dim3(512), 0, stream,
                           nh, te, Ag, Bg, Abg, Utg, btg, Uog, bog, Bp, bias, Ap);
        hipLaunchKernelGGL(tt_gemm_fb, dim3(1024), dim3(256), 0, stream,
                           nh, te, Bp, bias, out);
    }
}

// Round 14
// 165.228 us; speedup vs baseline: 2.3167x; 1.1861x over previous
//
#include <hip/hip_runtime.h>
#include <hip/hip_bf16.h>

// TensorTrainLMN: out[b, a*128+h] = X[b,:] @ W[:, a*128+h] + bias
//   X[b] = [nh[b,0,:128], ..., nh[b,15,:128], te[b,:128]]   (K = 2176)
//
// tt_prep (grid 2120 x 512, verified r13): blocks 0-67 fold W -> Bp bricks,
//   68-71 bias, 72+ convert nh/te -> Ap bricks. Brick = [kt-slice of 128 rows]
//   [slot=(k/8)&7][row128][8 bf16] = 16 KB, byte-linear staging unit.
// tt_gemm (NEW, m201 8-phase): 256x256xBK64, 512 thr (8 waves 2x4, wave
//   128x64), 128 KB LDS (one K-tile per parity buffer). Per phase: stage one
//   16KB half-tile via 2x global_load_lds | ds_read quadrant frags; barrier;
//   lgkm0+sched_barrier; setprio(1); 16 MFMA; setprio(0); barrier. Counted
//   vmcnt(2) at phases 3/7 only (stages ~4 phases in flight). No VALU, no
//   staging VGPRs in the loop.

typedef short bf16x8 __attribute__((ext_vector_type(8)));
typedef float f32x4  __attribute__((ext_vector_type(4)));

__device__ __forceinline__ unsigned f2bfbits(float f) {
    unsigned u = __builtin_bit_cast(unsigned, f);
    return (u + 0x7FFFu + ((u >> 16) & 1u)) >> 16;   // round-to-nearest-even
}
__device__ __forceinline__ unsigned pack2(float a, float b) {
    unsigned lo = (unsigned)__builtin_bit_cast(unsigned short, __float2bfloat16(a));
    unsigned hi = (unsigned)__builtin_bit_cast(unsigned short, __float2bfloat16(b));
    return lo | (hi << 16);
}

// ---------------------------------------------------------------------------
// Prep kernel: fold (bid<68), bias (68-71), cvt (72+). Verified r13.
// ---------------------------------------------------------------------------
#define FS 68

__global__ __launch_bounds__(512) void tt_prep(
    const float* __restrict__ nh,    // (32768,16,128)
    const float* __restrict__ te,    // (32768,128)
    const float* __restrict__ Ag,    // (4,128,64)
    const float* __restrict__ Bg,    // (4,64,64)
    const float* __restrict__ Abg,   // (4,1,64)
    const float* __restrict__ Utg,   // (4,128,64)
    const float* __restrict__ btg,   // (4,1,64)
    const float* __restrict__ Uog,   // (4,64,128)
    const float* __restrict__ bog,   // (4,1,128)
    unsigned short* __restrict__ Bp, // [4][34][8][128][8] bf16
    float* __restrict__ biasOut,     // [512]
    unsigned short* __restrict__ Ap) // [256][34][8][128][8] bf16
{
    __shared__ __align__(16) float L[23552];   // 92 KB (fold blocks only)
    const int t = threadIdx.x;
    const int bid = blockIdx.x;

    if (bid >= 72) {
        // ---- cvt: nh/te -> Ap tiled bf16 image ----
        const int cb = bid - 72;          // 0..2047
        const int mt = cb >> 3;
        const int r = t >> 2, q = t & 3;  // row 0..127, k-quarter (16 f32)
        for (int kt = cb & 7; kt < 34; kt += 8) {
            const float* src = (kt < 32)
                ? nh + ((size_t)(mt * 128 + r) * 2048 + kt * 64 + q * 16)
                : te + ((size_t)(mt * 128 + r) * 128 + (kt - 32) * 64 + q * 16);
            float4 v0 = ((const float4*)src)[0];
            float4 v1 = ((const float4*)src)[1];
            float4 v2 = ((const float4*)src)[2];
            float4 v3 = ((const float4*)src)[3];
            uint4 w0, w1;
            w0.x = pack2(v0.x, v0.y);  w0.y = pack2(v0.z, v0.w);
            w0.z = pack2(v1.x, v1.y);  w0.w = pack2(v1.z, v1.w);
            w1.x = pack2(v2.x, v2.y);  w1.y = pack2(v2.z, v2.w);
            w1.z = pack2(v3.x, v3.y);  w1.w = pack2(v3.z, v3.w);
            unsigned short* dst = Ap + (size_t)(mt * 34 + kt) * 8192;
            *(uint4*)(dst + (2 * q)     * 1024 + r * 8) = w0;  // slot 2q
            *(uint4*)(dst + (2 * q + 1) * 1024 + r * 8) = w1;  // slot 2q+1
        }
        return;
    }

    auto mm = [&](float* d, const float* x, const float* y, const float* add) {
        const int r = t >> 3, c0 = (t & 7) << 3;
        float acc[8];
#pragma unroll
        for (int j = 0; j < 8; ++j) acc[j] = 0.f;
        for (int k = 0; k < 64; ++k) {
            const float a = x[r * FS + k];
            const float4 y0 = *(const float4*)(y + k * FS + c0);
            const float4 y1 = *(const float4*)(y + k * FS + c0 + 4);
            acc[0] += a * y0.x; acc[1] += a * y0.y;
            acc[2] += a * y0.z; acc[3] += a * y0.w;
            acc[4] += a * y1.x; acc[5] += a * y1.y;
            acc[6] += a * y1.z; acc[7] += a * y1.w;
        }
        if (add) {
#pragma unroll
            for (int j = 0; j < 8; ++j) acc[j] += add[r * FS + c0 + j];
        }
#pragma unroll
        for (int j = 0; j < 8; ++j) d[r * FS + c0 + j] = acc[j];
    };

    float* buf[4];
    buf[0] = L;
    buf[1] = L + 4352;
    buf[2] = L + 8704;
    buf[3] = L + 13056;
    float* const Pbuf = L + 17408;   // 64x64 dense (stride 64)
    float* const UC   = L + 21504;   // 16x128 staging

    if (bid < 68) {
        int a, p, kbase;
        const float* src;
        if (bid < 64) { a = bid >> 4; const int c = bid & 15; p = 15 - c; kbase = c * 128; src = Ag  + a * 8192; }
        else          { a = bid - 64; p = 16; kbase = 2048;               src = Utg + a * 8192; }
        const float* Bmat = Bg + a * 4096;

        for (int i = t; i < 4096; i += 512) {
            const int row = i >> 6, col = i & 63;
            buf[0][row * FS + col] = Bmat[i];
            buf[2][row * FS + col] = (row == col) ? 1.f : 0.f;
        }
        __syncthreads();
        int bcur = 0, rcur = 2;
        int e = p;
        while (e) {
            if (e & 1) { mm(buf[rcur ^ 1], buf[rcur], buf[bcur], nullptr); rcur ^= 1; __syncthreads(); }
            e >>= 1;
            if (e)     { mm(buf[bcur ^ 1], buf[bcur], buf[bcur], nullptr); bcur ^= 1; __syncthreads(); }
        }

        {
            const int prow = t >> 3, pc0 = (t & 7) << 3;
#pragma unroll
            for (int j = 0; j < 8; ++j)
                Pbuf[prow * 64 + pc0 + j] = buf[rcur][prow * FS + pc0 + j];
        }
        __syncthreads();

        // M1 = src(128x64) @ P, stored stride-65 at L
        float* M1 = L;
        {
            const int i = t >> 2, r0 = (t & 3) << 4;
            float acc[16];
#pragma unroll
            for (int j = 0; j < 16; ++j) acc[j] = 0.f;
            for (int q = 0; q < 64; ++q) {
                const float av = src[i * 64 + q];
                const float4* pr = (const float4*)(Pbuf + q * 64 + r0);
#pragma unroll
                for (int jj = 0; jj < 4; ++jj) {
                    float4 v = pr[jj];
                    acc[4 * jj + 0] += av * v.x;
                    acc[4 * jj + 1] += av * v.y;
                    acc[4 * jj + 2] += av * v.z;
                    acc[4 * jj + 3] += av * v.w;
                }
            }
#pragma unroll
            for (int j = 0; j < 16; ++j) M1[i * 65 + r0 + j] = acc[j];
        }
        __syncthreads();

        // W2 = M1(128x64) @ Uo(64x128)
        const float* UoA = Uog + a * 8192;
        const int i = t >> 2, h0 = (t & 3) << 5;
        float acc2[32];
#pragma unroll
        for (int j = 0; j < 32; ++j) acc2[j] = 0.f;
        for (int ch = 0; ch < 4; ++ch) {
            __syncthreads();
            for (int idx = t; idx < 2048; idx += 512) UC[idx] = UoA[ch * 2048 + idx];
            __syncthreads();
            for (int rr = 0; rr < 16; ++rr) {
                const float m = M1[i * 65 + ch * 16 + rr];
                const float4* ur = (const float4*)(UC + rr * 128 + h0);
#pragma unroll
                for (int jj = 0; jj < 8; ++jj) {
                    float4 v = ur[jj];
                    acc2[4 * jj + 0] += m * v.x;
                    acc2[4 * jj + 1] += m * v.y;
                    acc2[4 * jj + 2] += m * v.z;
                    acc2[4 * jj + 3] += m * v.w;
                }
            }
        }
        // write Bp brick: [nb = n>>7][kt][slot][nloc = n&127][8]
        {
            const int k = kbase + i;
            const int kt = k >> 6, slot = (k >> 3) & 7, widx = k & 7;
#pragma unroll
            for (int j = 0; j < 32; ++j) {
                const int n = a * 128 + h0 + j;
                Bp[((size_t)(((n >> 7) * 34 + kt) * 8 + slot)) * 1024 + (n & 127) * 8 + widx] =
                    (unsigned short)f2bfbits(acc2[j]);
            }
        }
    } else {
        // bias: S16 = sum_{p<16} B^p, B16 = B^16
        const int a = bid - 68;
        const float* Bmat = Bg + a * 4096;
        for (int i = t; i < 4096; i += 512) {
            const int row = i >> 6, col = i & 63;
            buf[0][row * FS + col] = Bmat[i];
            buf[2][row * FS + col] = (row == col) ? 1.f : 0.f;
        }
        __syncthreads();
        int bcur = 0, scur = 2;
        for (int rnd = 0; rnd < 4; ++rnd) {
            mm(buf[scur ^ 1], buf[bcur], buf[scur], buf[scur]);
            mm(buf[bcur ^ 1], buf[bcur], buf[bcur], nullptr);
            __syncthreads();
            scur ^= 1; bcur ^= 1;
        }
        float* vv = Pbuf;
        if (t < 64) {
            float acc = 0.f;
            const float* S16 = buf[scur];
            const float* B16 = buf[bcur];
            for (int q = 0; q < 64; ++q)
                acc += Abg[a * 64 + q] * S16[q * FS + t]
                     + btg[a * 64 + q] * B16[q * FS + t];
            vv[t] = acc;
        }
        __syncthreads();
        if (t < 128) {
            float accb = bog[a * 128 + t];
            const float* UoA = Uog + a * 8192;
            for (int r = 0; r < 64; ++r) accb += vv[r] * UoA[r * 128 + t];
            biasOut[a * 128 + t] = accb;
        }
    }
}
#undef FS

// ---------------------------------------------------------------------------
// m201 8-phase GEMM: 256 blocks x 512 thr. Tile 256x256, BK=64 (34 K-tiles,
// 17 pairs). Buffers: K-tile parity p -> buf p. Stage unit = 16KB brick.
// ---------------------------------------------------------------------------
__global__ __launch_bounds__(512) void tt_gemm(
    const unsigned short* __restrict__ Ap,  // [256][34][8][128][8]
    const unsigned short* __restrict__ Bp,  // [4][34][8][128][8]
    const float* __restrict__ bias,         // [512]
    float* __restrict__ out)                // (32768,512)
{
    __shared__ __align__(16) char Lds[131072];  // A 2x32K @0, B 2x32K @64K

    const int t = threadIdx.x;
    const int lane = t & 63, w = t >> 6;
    const int lt = (blockIdx.x & 7) * 32 + (blockIdx.x >> 3);   // 256 = 8*32
    const int m0 = (lt >> 1) * 256;
    const int nblk = lt & 1;
    const int wr = w >> 2, wc = w & 3;
    const int lx = lane & 15, lg = lane >> 4;

    // stage source bases (per-lane); brick (idx,kt) at + (idx*34+kt)*16384
    const char* const apb = (const char*)Ap + (size_t)(m0 >> 7) * 34 * 16384
                            + w * 1024 + lane * 16;
    const char* const bpb = (const char*)Bp + (size_t)(nblk * 2) * 34 * 16384
                            + w * 1024 + lane * 16;
    char* const La = Lds;            // + d*32768 + h*16384 + j*8192 + w*1024
    char* const Lb = Lds + 65536;

    // frag read offsets
    const int aro = wr * 16384 + lx * 16;   // + d*32768 + (kk*4+lg)*2048 + fm*256
    int bco[4];
#pragma unroll
    for (int fn = 0; fn < 4; ++fn) {
        const int col = wc * 64 + fn * 16 + lx;
        bco[fn] = (col >> 7) * 16384 + (col & 127) * 16;
    }

    f32x4 acc[8][4] = {};
    bf16x8 aF0[4][2], aF1[4][2], bF0[2][2], bF1[2][2];

#define BAR()  __builtin_amdgcn_s_barrier()
#define LGKM0() do { asm volatile("s_waitcnt lgkmcnt(0)" ::: "memory"); \
                     __builtin_amdgcn_sched_barrier(0); } while (0)
#define PRIO(x) __builtin_amdgcn_s_setprio(x)
#define VM(NSTR) asm volatile("s_waitcnt vmcnt(" NSTR ")" ::: "memory")

#define STAGEA(d_, h_, kt_) do {                                               \
    const char* _s = apb + (size_t)((h_) * 34 + (kt_)) * 16384;                \
    char* _d = La + (d_) * 32768 + (h_) * 16384 + w * 1024;                    \
    __builtin_amdgcn_global_load_lds(                                          \
        (const __attribute__((address_space(1))) unsigned int*)_s,             \
        (__attribute__((address_space(3))) unsigned int*)_d, 16, 0, 0);        \
    __builtin_amdgcn_global_load_lds(                                          \
        (const __attribute__((address_space(1))) unsigned int*)(_s + 8192),    \
        (__attribute__((address_space(3))) unsigned int*)(_d + 8192), 16, 0, 0); \
} while (0)

#define STAGEB(d_, h_, kt_) do {                                               \
    const char* _s = bpb + (size_t)((h_) * 34 + (kt_)) * 16384;                \
    char* _d = Lb + (d_) * 32768 + (h_) * 16384 + w * 1024;                    \
    __builtin_amdgcn_global_load_lds(                                          \
        (const __attribute__((address_space(1))) unsigned int*)_s,             \
        (__attribute__((address_space(3))) unsigned int*)_d, 16, 0, 0);        \
    __builtin_amdgcn_global_load_lds(                                          \
        (const __attribute__((address_space(1))) unsigned int*)(_s + 8192),    \
        (__attribute__((address_space(3))) unsigned int*)(_d + 8192), 16, 0, 0); \
} while (0)

#define RDA(dst, d_, fmb) do {                                                 \
    _Pragma("unroll")                                                          \
    for (int _f = 0; _f < 4; ++_f)                                             \
        _Pragma("unroll")                                                      \
        for (int _k = 0; _k < 2; ++_k)                                         \
            dst[_f][_k] = *(const bf16x8*)(La + (d_) * 32768 +                 \
                (_k * 4 + lg) * 2048 + aro + ((fmb) + _f) * 256);              \
} while (0)

#define RDB(dst, d_, fnb) do {                                                 \
    _Pragma("unroll")                                                          \
    for (int _f = 0; _f < 2; ++_f)                                             \
        _Pragma("unroll")                                                      \
        for (int _k = 0; _k < 2; ++_k)                                         \
            dst[_f][_k] = *(const bf16x8*)(Lb + (d_) * 32768 +                 \
                (_k * 4 + lg) * 2048 + bco[(fnb) + _f]);                       \
} while (0)

#define QMFMA(fmb, fnb, af, bf) do {                                           \
    _Pragma("unroll")                                                          \
    for (int _f = 0; _f < 4; ++_f)                                             \
        _Pragma("unroll")                                                      \
        for (int _n = 0; _n < 2; ++_n)                                         \
            _Pragma("unroll")                                                  \
            for (int _k = 0; _k < 2; ++_k)                                     \
                acc[(fmb) + _f][(fnb) + _n] =                                  \
                    __builtin_amdgcn_mfma_f32_16x16x32_bf16(                   \
                        af[_f][_k], bf[_n][_k],                                \
                        acc[(fmb) + _f][(fnb) + _n], 0, 0, 0);                 \
} while (0)

    // prologue: tile0 (buf0, 4 halves) + Ah0 of tile1 (the "(-1).p7" slot)
    STAGEA(0, 0, 0); STAGEA(0, 1, 0);
    STAGEB(0, 0, 0); STAGEB(0, 1, 0);
    STAGEA(1, 0, 1);
    asm volatile("s_waitcnt vmcnt(0)" ::: "memory");
    BAR();

#pragma unroll 1
    for (int i = 0; i < 17; ++i) {
        const int t1 = 2 * i + 1;
        const int ta = 2 * i + 2, tb = 2 * i + 3;   // tiles staged this pair
        const bool ga = ta < 34, gb = tb < 34;

        // ===== phase 0: tile t0 (buf0) Q00 =====
        STAGEA(1, 1, t1);
        RDA(aF0, 0, 0);
        RDB(bF0, 0, 0);
        BAR(); LGKM0(); PRIO(1);
        QMFMA(0, 0, aF0, bF0);
        PRIO(0); BAR();

        // ===== phase 1: Q01 =====
        STAGEB(1, 0, t1);
        RDB(bF1, 0, 2);
        BAR(); LGKM0(); PRIO(1);
        QMFMA(0, 2, aF0, bF1);
        PRIO(0); BAR();

        // ===== phase 2: Q10 =====
        STAGEB(1, 1, t1);
        RDA(aF1, 0, 4);
        BAR(); LGKM0(); PRIO(1);
        QMFMA(4, 0, aF1, bF0);
        PRIO(0); BAR();

        // ===== phase 3: Q11 (+ Ah0 of ta; counted wait) =====
        if (ga) STAGEA(0, 0, ta);
        BAR(); PRIO(1);
        QMFMA(4, 2, aF1, bF1);
        PRIO(0);
        if (ga) VM("2"); else VM("0");
        BAR();

        // ===== phase 4: tile t1 (buf1) Q00 =====
        if (ga) STAGEA(0, 1, ta);
        RDA(aF0, 1, 0);
        RDB(bF0, 1, 0);
        BAR(); LGKM0(); PRIO(1);
        QMFMA(0, 0, aF0, bF0);
        PRIO(0); BAR();

        // ===== phase 5: Q01 =====
        if (ga) STAGEB(0, 0, ta);
        RDB(bF1, 1, 2);
        BAR(); LGKM0(); PRIO(1);
        QMFMA(0, 2, aF0, bF1);
        PRIO(0); BAR();

        // ===== phase 6: Q10 =====
        if (ga) STAGEB(0, 1, ta);
        RDA(aF1, 1, 4);
        BAR(); LGKM0(); PRIO(1);
        QMFMA(4, 0, aF1, bF0);
        PRIO(0); BAR();

        // ===== phase 7: Q11 (+ Ah0 of tb; counted wait) =====
        if (gb) STAGEA(1, 0, tb);
        BAR(); PRIO(1);
        QMFMA(4, 2, aF1, bF1);
        PRIO(0);
        if (gb) VM("2"); else VM("0");
        BAR();
    }

#undef QMFMA
#undef RDB
#undef RDA
#undef STAGEB
#undef STAGEA
#undef VM
#undef PRIO
#undef LGKM0
#undef BAR

    // epilogue: C/D layout col = lane&15, row = (lane>>4)*4 + reg  [m89]
    const int orow = m0 + wr * 128 + lg * 4;
    const int ocol = nblk * 256 + wc * 64 + lx;
    float bv[4];
#pragma unroll
    for (int fn = 0; fn < 4; ++fn) bv[fn] = bias[ocol + fn * 16];
#pragma unroll
    for (int fm = 0; fm < 8; ++fm)
#pragma unroll
        for (int fn = 0; fn < 4; ++fn)
#pragma unroll
            for (int j = 0; j < 4; ++j)
                out[(size_t)(orow + fm * 16 + j) * 512 + ocol + fn * 16] =
                    acc[fm][fn][j] + bv[fn];
}

// ---------------------------------------------------------------------------
// Fallback GEMM (ws too small for Ap): r13's, unchanged.
// ---------------------------------------------------------------------------
#define SYNC_NODRAIN() do {                                   \
    asm volatile("s_waitcnt lgkmcnt(0)" ::: "memory");        \
    __builtin_amdgcn_s_barrier();                             \
} while (0)

__global__ __launch_bounds__(256) void tt_gemm_fb(
    const float* __restrict__ nh,
    const float* __restrict__ te,
    const unsigned short* __restrict__ Bp,  // [4][34][8][128][8]
    const float* __restrict__ bias,
    float* __restrict__ out)
{
    __shared__ __align__(16) char Ab[16384];

    const int t = threadIdx.x;
    const int lane = t & 63, wave = t >> 6;
    const int lt = (blockIdx.x & 7) * 128 + (blockIdx.x >> 3);
    const int m0 = (lt >> 1) * 64;
    const int wc = (lt & 1) * 4 + wave;          // n-group 0..7
    const int lx = lane & 15, lg = lane >> 4;

    const int r = t >> 2, c = t & 3;
    const float* nhp = nh + (size_t)(m0 + r) * 2048 + c * 16;
    const float* tep = te + (size_t)(m0 + r) * 128  + c * 16;
    const int awoff = (c >> 1) * 4096 + (c & 1) * 2048 + r * 16;
    const int aroff = lg * 1024 + lx * 16;

    const char* const wbase = (const char*)Bp + (size_t)(wc >> 1) * 557056
                              + ((wc & 1) * 64 + lx) * 16 + lg * 2048;

    f32x4 acc[4][4] = {};
    float4 va0[4], va1[4];
    uint4  bF0[4][2], bF1[4][2];

#define LOADA(dst, kt_) do {                                                   \
    const float* _p = ((kt_) < 32) ? (nhp + (kt_) * 64) : (tep + ((kt_) - 32) * 64); \
    _Pragma("unroll")                                                          \
    for (int _j = 0; _j < 4; ++_j) dst[_j] = *(const float4*)(_p + 4 * _j);    \
} while (0)

#define WRITEA(src, d_) do {                                                   \
    uint4 _w0, _w1;                                                            \
    _w0.x = pack2(src[0].x, src[0].y);  _w0.y = pack2(src[0].z, src[0].w);     \
    _w0.z = pack2(src[1].x, src[1].y);  _w0.w = pack2(src[1].z, src[1].w);     \
    _w1.x = pack2(src[2].x, src[2].y);  _w1.y = pack2(src[2].z, src[2].w);     \
    _w1.z = pack2(src[3].x, src[3].y);  _w1.w = pack2(src[3].z, src[3].w);     \
    *(uint4*)(Ab + (d_) * 8192 + awoff)        = _w0;                          \
    *(uint4*)(Ab + (d_) * 8192 + awoff + 1024) = _w1;                          \
} while (0)

#define LOADB(dst, kt_) do {                                                   \
    const char* _q = wbase + (size_t)(kt_) * 16384;                            \
    _Pragma("unroll")                                                          \
    for (int _kk = 0; _kk < 2; ++_kk)                                          \
        _Pragma("unroll")                                                      \
        for (int _fn = 0; _fn < 4; ++_fn)                                      \
            dst[_fn][_kk] = *(const uint4*)(_q + _kk * 8192 + _fn * 256);      \
} while (0)

#define COMPUTE(d_, bsrc) do {                                                 \
    _Pragma("unroll")                                                          \
    for (int _kk = 0; _kk < 2; ++_kk) {                                        \
        bf16x8 _aF[4];                                                         \
        _Pragma("unroll")                                                      \
        for (int _fm = 0; _fm < 4; ++_fm)                                      \
            _aF[_fm] = *(const bf16x8*)(Ab + (d_) * 8192 + _kk * 4096 + aroff + _fm * 256); \
        _Pragma("unroll")                                                      \
        for (int _fm = 0; _fm < 4; ++_fm)                                      \
            _Pragma("unroll")                                                  \
            for (int _fn = 0; _fn < 4; ++_fn)                                  \
                acc[_fm][_fn] = __builtin_amdgcn_mfma_f32_16x16x32_bf16(       \
                    _aF[_fm], __builtin_bit_cast(bf16x8, bsrc[_fn][_kk]),      \
                    acc[_fm][_fn], 0, 0, 0);                                   \
    }                                                                          \
} while (0)

    LOADA(va0, 0);
    WRITEA(va0, 0);
    LOADA(va1, 1);
    LOADA(va0, 2);
    LOADB(bF0, 0);
    LOADB(bF1, 1);
    SYNC_NODRAIN();

#pragma unroll 1
    for (int kt = 0; kt < 34; kt += 2) {
        WRITEA(va1, 1);
        if (kt + 3 < 34) LOADA(va1, kt + 3);
        COMPUTE(0, bF0);
        if (kt + 2 < 34) LOADB(bF0, kt + 2);
        SYNC_NODRAIN();

        if (kt + 2 < 34) {
            WRITEA(va0, 0);
            if (kt + 4 < 34) LOADA(va0, kt + 4);
        }
        COMPUTE(1, bF1);
        if (kt + 3 < 34) LOADB(bF1, kt + 3);
        SYNC_NODRAIN();
    }
#undef LOADA
#undef WRITEA
#undef LOADB
#undef COMPUTE

    const int orow = m0 + lg * 4;
    const int ocol = wc * 64 + lx;
    float bv[4];
#pragma unroll
    for (int fn = 0; fn < 4; ++fn) bv[fn] = bias[ocol + fn * 16];
#pragma unroll
    for (int fm = 0; fm < 4; ++fm)
#pragma unroll
        for (int fn = 0; fn < 4; ++fn)
#pragma unroll
            for (int j = 0; j < 4; ++j)
                out[(size_t)(orow + fm * 16 + j) * 512 + ocol + fn * 16] =
                    acc[fm][fn][j] + bv[fn];
}

// ---------------------------------------------------------------------------
extern "C" void kernel_launch(void* const* d_in, const int* in_sizes, int n_in,
                              void* d_out, int out_size, void* d_ws, size_t ws_size,
                              hipStream_t stream) {
    const float* nh  = (const float*)d_in[0];
    const float* te  = (const float*)d_in[1];
    const float* Ag  = (const float*)d_in[2];
    const float* Bg  = (const float*)d_in[3];
    const float* Abg = (const float*)d_in[4];
    const float* Utg = (const float*)d_in[5];
    const float* btg = (const float*)d_in[6];
    const float* Uog = (const float*)d_in[7];
    const float* bog = (const float*)d_in[8];

    unsigned short* Bp = (unsigned short*)d_ws;               // 2,228,224 B
    float* bias = (float*)((char*)d_ws + 2228224);            // 2,048 B
    unsigned short* Ap = (unsigned short*)((char*)d_ws + 2230272); // 142.6 MB
    float* out = (float*)d_out;

    const bool fast = ws_size >= (size_t)144836608;

    if (fast) {
        hipLaunchKernelGGL(tt_prep, dim3(72 + 2048), dim3(512), 0, stream,
                           nh, te, Ag, Bg, Abg, Utg, btg, Uog, bog, Bp, bias, Ap);
        hipLaunchKernelGGL(tt_gemm, dim3(256), dim3(512), 0, stream,
                           Ap, Bp, bias, out);
    } else {
        hipLaunchKernelGGL(tt_prep, dim3(72), dim3(512), 0, stream,
                           nh, te, Ag, Bg, Abg, Utg, btg, Uog, bog, Bp, bias, Ap);
        hipLaunchKernelGGL(tt_gemm_fb, dim3(1024), dim3(256), 0, stream,
                           nh, te, Bp, bias, out);
    }
}